// Round 2
// baseline (230.085 us; speedup 1.0000x reference)
//
#include <hip/hip_runtime.h>

// TemporalPSPGate: state_t = ALPHA*state_{t-1} + x_t ; out_t = x_t * sigmoid(state_t)
// x: (T,B,H,N,D) = (16,16,8,256,64) fp32.
//
// Session journal:
// R1: compiler serialized load->use (VGPR=28), kernel 83us.
// R2: 16-deep register prefetch -> kernel ~66us (dur_us 230.7 = 2x~82us fills + kernel).
// R3: nt loads/stores + v_rcp: NEUTRAL (kernel still ~67us). Cache churn theory dead.
// R4 (this): 16-deep prefetch costs ~64 data VGPRs -> ~5 waves/SIMD. Copy kernels
//   that hit 6.3 TB/s run 8 waves/SIMD. TLP, not per-wave MLP, is the remaining
//   lever (R1->R2: 16x depth bought only 1.26x). Rotating 8-deep prefetch with
//   static indices + __launch_bounds__(256,8) caps VGPR<=64 -> 8 waves/SIMD,
//   all 2048 blocks resident. nt kept on loads only (keep L3 for write absorption).
//   Predicted: kernel 66 -> ~52-56us, dur_us -> ~212-218.

#define T_STEPS 16
#define SPATIAL (16LL * 8LL * 256LL * 64LL)   // B*H*N*D = 2,097,152 floats per t
#define VEC4    (SPATIAL / 4)                 // 524,288 float4 slots per t
#define ALPHA_F 0.60653065971263342f          // exp(-1/2)
#define PF_DEPTH 8

typedef float f32x4 __attribute__((ext_vector_type(4)));

__global__ __launch_bounds__(256, 8) void
TemporalPSPGate_35613868819159_kernel(const f32x4* __restrict__ x,
                                      f32x4* __restrict__ out) {
    const int i = blockIdx.x * 256 + threadIdx.x;   // float4 slot, [0, VEC4)

    // Rotating 8-deep prefetch buffer. Fully unrolled loops -> all xv indices
    // are compile-time constants (runtime-indexed ext_vector arrays spill to
    // scratch). 8 float4 = 32 data VGPRs, leaving room for 8 waves/SIMD.
    f32x4 xv[PF_DEPTH];
    #pragma unroll
    for (int t = 0; t < PF_DEPTH; ++t) {
        xv[t] = __builtin_nontemporal_load(x + (long long)t * VEC4 + i);
    }

    f32x4 st = {0.f, 0.f, 0.f, 0.f};
    #pragma unroll
    for (int t = 0; t < T_STEPS; ++t) {
        const f32x4 xt = xv[t & (PF_DEPTH - 1)];

        // Refill this slot for t+8 immediately after consumption: keeps 8
        // loads in flight for the whole wave lifetime (modulo schedule).
        if (t + PF_DEPTH < T_STEPS) {
            xv[t & (PF_DEPTH - 1)] =
                __builtin_nontemporal_load(x + (long long)(t + PF_DEPTH) * VEC4 + i);
        }

        st = ALPHA_F * st + xt;

        f32x4 o;
        #pragma unroll
        for (int c = 0; c < 4; ++c) {
            const float e = __expf(-st[c]);
            o[c] = xt[c] * __builtin_amdgcn_rcpf(1.0f + e);
        }
        // Plain (cached) store: L3 absorbs/smooths the write bursts.
        out[(long long)t * VEC4 + i] = o;
    }
}

extern "C" void kernel_launch(void* const* d_in, const int* in_sizes, int n_in,
                              void* d_out, int out_size, void* d_ws, size_t ws_size,
                              hipStream_t stream) {
    const f32x4* x = (const f32x4*)d_in[0];
    f32x4* out = (f32x4*)d_out;

    const int block = 256;
    const int grid = (int)(VEC4 / block);   // 2048 blocks; 8/CU, fully resident

    TemporalPSPGate_35613868819159_kernel<<<grid, block, 0, stream>>>(x, out);
}

// Round 3
// 217.572 us; speedup vs baseline: 1.0575x; 1.0575x over previous
//
#include <hip/hip_runtime.h>

// TemporalPSPGate: state_t = ALPHA*state_{t-1} + x_t ; out_t = x_t * sigmoid(state_t)
// x: (T,B,H,N,D) = (16,16,8,256,64) fp32.
//
// Session journal:
// R1: compiler serialized load->use (VGPR=28), kernel 83us.
// R2: 16-deep register prefetch -> kernel ~66us. (dur = kernel + ~163us harness fills)
// R3: nt loads/stores + v_rcp: NEUTRAL. Cache-churn theory dead.
// R4: rotating-8 prefetch + 8 waves/SIMD: NEUTRAL. TLP theory dead.
//     Kernel pinned at ~64-70us = 4.0 TB/s vs 6.29 TB/s copy ceiling.
// R5 (this): only untested structural delta vs a 6.3 TB/s copy: DRAM run length.
//   Current wave interleaves 16R+16W streams in 1KB bursts. Remap: thread owns 4
//   wave-consecutive float4s (j, j+64, j+128, j+192) -> each wave does 4 back-to-back
//   coalesced 1KB loads = 4KB contiguous run per slice, same for stores. Rotating
//   2-slice prefetch (8 loads in flight/wave; 2048 waves -> 16MB in flight >> 6MB
//   BW-latency product). Predicted: kernel ~50us, dur ~215. If neutral -> roofline.

#define T_STEPS 16
#define SPATIAL (16LL * 8LL * 256LL * 64LL)   // B*H*N*D = 2,097,152 floats per t
#define VEC4    (SPATIAL / 4)                 // 524,288 float4 slots per t
#define ALPHA_F 0.60653065971263342f          // exp(-1/2)
#define SUB     4                             // consecutive wave-chunks per thread

typedef float f32x4 __attribute__((ext_vector_type(4)));

__global__ __launch_bounds__(256) void
TemporalPSPGate_35613868819159_kernel(const f32x4* __restrict__ x,
                                      f32x4* __restrict__ out) {
    // wave w of block b owns f4 slots [wb, wb+256) per slice; lane handles
    // wb+lane + 64*s for s=0..3 -> every wave-load is 1KB coalesced and the
    // 4 loads per slice form one 4KB contiguous run.
    const int tid  = threadIdx.x;
    const int wave = tid >> 6;
    const int lane = tid & 63;
    const long long wb = ((long long)blockIdx.x * 4 + wave) * 256;
    const long long j  = wb + lane;            // base f4 slot

    // Rotating 2-slice prefetch; all indices compile-time (no scratch).
    f32x4 xv[2][SUB];
    #pragma unroll
    for (int tt = 0; tt < 2; ++tt)
        #pragma unroll
        for (int s = 0; s < SUB; ++s)
            xv[tt][s] = __builtin_nontemporal_load(
                x + (long long)tt * VEC4 + j + 64 * s);

    f32x4 st[SUB];
    #pragma unroll
    for (int s = 0; s < SUB; ++s) st[s] = (f32x4){0.f, 0.f, 0.f, 0.f};

    #pragma unroll
    for (int t = 0; t < T_STEPS; ++t) {
        const int cur = t & 1;

        f32x4 xt[SUB];
        #pragma unroll
        for (int s = 0; s < SUB; ++s) xt[s] = xv[cur][s];

        // Prefetch slice t+2 into the slot just consumed (4KB burst).
        if (t + 2 < T_STEPS) {
            #pragma unroll
            for (int s = 0; s < SUB; ++s)
                xv[cur][s] = __builtin_nontemporal_load(
                    x + (long long)(t + 2) * VEC4 + j + 64 * s);
        }

        // Recurrence + gate; stores grouped -> 4KB contiguous write run.
        #pragma unroll
        for (int s = 0; s < SUB; ++s) {
            st[s] = ALPHA_F * st[s] + xt[s];
            f32x4 o;
            #pragma unroll
            for (int c = 0; c < 4; ++c) {
                const float e = __expf(-st[s][c]);
                o[c] = xt[s][c] * __builtin_amdgcn_rcpf(1.0f + e);
            }
            out[(long long)t * VEC4 + j + 64 * s] = o;
        }
    }
}

extern "C" void kernel_launch(void* const* d_in, const int* in_sizes, int n_in,
                              void* d_out, int out_size, void* d_ws, size_t ws_size,
                              hipStream_t stream) {
    const f32x4* x = (const f32x4*)d_in[0];
    f32x4* out = (f32x4*)d_out;

    const int block = 256;
    const int grid = (int)(VEC4 / (block * SUB));   // 512 blocks, no tail

    TemporalPSPGate_35613868819159_kernel<<<grid, block, 0, stream>>>(x, out);
}